// Round 5
// baseline (591.028 us; speedup 1.0000x reference)
//
#include <hip/hip_runtime.h>

#define NNODES 100000
#define NEDGES 1600000
#define DIM    128
#define OUTD   32
#define NGRAPH 512
#define LDA    136   // padded LDS stride (bf16 elems)

#define NBUCK2  256                          // coarse buckets: dst >> 9
#define BSHIFT  9
#define CAP     12288                        // per-bucket region capacity (mean 8163)
#define EPB2    8192
#define SBLOCKS ((NEDGES + EPB2 - 1) / EPB2) // 196
#define NBUILD  ((NNODES + 511) / 512)       // 196
#define FBLOCKS ((NNODES + 127) / 128)       // 782

using bf16x8 = __attribute__((ext_vector_type(8))) short;
using f32x4  = __attribute__((ext_vector_type(4))) float;

__device__ __forceinline__ short f2bf(float f) {
    unsigned u = __float_as_uint(f);
    unsigned r = (u + 0x7fff + ((u >> 16) & 1)) >> 16;   // RNE
    return (short)r;
}
__device__ __forceinline__ float bf2f_lo(unsigned u) { return __uint_as_float(u << 16); }
__device__ __forceinline__ float bf2f_hi(unsigned u) { return __uint_as_float(u & 0xffff0000u); }

// ============================================================
// Weight pre-transpose: WT[mat][n][k] = bf16(W[mat][k][n])
// ============================================================
__global__ __launch_bounds__(256) void k_prepW(
    const float* __restrict__ W, short* __restrict__ WT, int nmat)
{
    int idx = blockIdx.x * 256 + threadIdx.x;
    if (idx >= nmat * DIM * DIM) return;
    int mat = idx >> 14;
    int rem = idx & 16383;
    int k = rem >> 7, n = rem & 127;
    WT[(size_t)mat * 16384 + n * DIM + k] = f2bf(W[(size_t)mat * 16384 + k * DIM + n]);
}

// ============================================================
// Fused encoder: x -> relu(xW1+b1) -> relu(..W2+b2) -> (..Wg0)*inv -> hw0
// 512 thr / 128 rows per block. Three chained MFMA GEMMs, h in LDS.
// WT holds 3 transposed bf16 mats: enc_W1, enc_W2, gcn_W0.
// ============================================================
__global__ __launch_bounds__(512, 4) void k_enc(
    const float* __restrict__ x, const short* __restrict__ WT,
    const float* __restrict__ b1, const float* __restrict__ b2,
    const float* __restrict__ inv, short* __restrict__ hw0, int M)
{
    __shared__ short As[128 * LDA];
    __shared__ short Bs[128 * LDA];

    const int tid = threadIdx.x;
    const int m0  = blockIdx.x * 128;

    // ---- stage x (fp32 -> bf16): lane: row=tid>>2, 32-feat chunk = (tid&3)*32
    {
        const int row = tid >> 2, ch = (tid & 3) * 32;
        const int gr  = min(m0 + row, M - 1);
        const float4* sp = (const float4*)(x + (size_t)gr * DIM + ch);
        #pragma unroll
        for (int c = 0; c < 4; ++c) {
            float4 f0 = sp[c * 2], f1 = sp[c * 2 + 1];
            short t8[8] = { f2bf(f0.x), f2bf(f0.y), f2bf(f0.z), f2bf(f0.w),
                            f2bf(f1.x), f2bf(f1.y), f2bf(f1.z), f2bf(f1.w) };
            *(bf16x8*)&As[row * LDA + ch + c * 8] = *(bf16x8*)t8;
        }
    }

    const int wave = tid >> 6, lane = tid & 63;
    const int ml = lane & 15, quad = lane >> 4;
    const int w16 = wave * 16;
    const int brow = tid >> 2, bch = (tid & 3) * 32;

    #pragma unroll
    for (int mat = 0; mat < 3; ++mat) {
        if (mat > 0) __syncthreads();   // all waves done reading old Bs
        // stage Bs[mat]
        const short* wt = WT + (size_t)mat * 16384 + brow * DIM + bch;
        #pragma unroll
        for (int c = 0; c < 4; ++c)
            *(bf16x8*)&Bs[brow * LDA + bch + c * 8] = *(const bf16x8*)(wt + c * 8);
        __syncthreads();

        f32x4 acc[8] = {};
        #pragma unroll
        for (int kk = 0; kk < 4; ++kk) {
            const int k0 = kk * 32 + quad * 8;
            bf16x8 a = *(bf16x8*)&As[(w16 + ml) * LDA + k0];
            #pragma unroll
            for (int ni = 0; ni < 8; ++ni) {
                bf16x8 b = *(bf16x8*)&Bs[(ni * 16 + ml) * LDA + k0];
                acc[ni] = __builtin_amdgcn_mfma_f32_16x16x32_bf16(a, b, acc[ni], 0, 0, 0);
            }
        }
        // epilogue -> wave-local rows of As (C-layout -> A-layout via LDS)
        #pragma unroll
        for (int ni = 0; ni < 8; ++ni) {
            const int colc = ni * 16 + ml;
            #pragma unroll
            for (int r = 0; r < 4; ++r) {
                const int rowl = w16 + quad * 4 + r;
                float v = acc[ni][r];
                if (mat == 0)      v = fmaxf(v + b1[colc], 0.f);
                else if (mat == 1) v = fmaxf(v + b2[colc], 0.f);
                else               v *= inv[min(m0 + rowl, M - 1)];
                As[rowl * LDA + colc] = f2bf(v);
            }
        }
    }

    // ---- store (wave-local rows)
    const int srow = w16 + (lane >> 2), sch = (lane & 3) * 32;
    const int grow = m0 + srow;
    if (grow < M) {
        #pragma unroll
        for (int c = 0; c < 4; ++c)
            *(bf16x8*)(hw0 + (size_t)grow * DIM + sch + c * 8) =
                *(bf16x8*)&As[srow * LDA + sch + c * 8];
    }
}

// ============================================================
// Fused agg + GEMM: h = relu(inv*(hw_in[n] + sum hw_in[src]) + bias)
//                   hw_out = (h @ W)*inv        (W given as bf16 W^T)
// 512 thr / 128 nodes per block; wave w gathers its own 16-node m-tile.
// ============================================================
__global__ __launch_bounds__(512, 4) void k_agggemm(
    const short* __restrict__ hw_in, const int* __restrict__ row_off,
    const int* __restrict__ cntA, const int* __restrict__ col,
    const float* __restrict__ inv, const float* __restrict__ bias,
    const short* __restrict__ WT, short* __restrict__ hw_out)
{
    __shared__ short As[128 * LDA];
    __shared__ short Bs[128 * LDA];

    const int tid = threadIdx.x;
    const int m0  = blockIdx.x * 128;
    const int wave = tid >> 6, lane = tid & 63;

    // ---- stage Bs
    {
        const int brow = tid >> 2, bch = (tid & 3) * 32;
        const short* wt = WT + brow * DIM + bch;
        #pragma unroll
        for (int c = 0; c < 4; ++c)
            *(bf16x8*)&Bs[brow * LDA + bch + c * 8] = *(const bf16x8*)(wt + c * 8);
    }

    // ---- gather phase: wave handles nodes m0+wave*16 .. +15
    {
        const unsigned* hp = (const unsigned*)hw_in;
        const float2 bb = ((const float2*)bias)[lane];
        #pragma unroll 1
        for (int i = 0; i < 16; ++i) {
            const int node = m0 + wave * 16 + i;
            unsigned packed = 0;
            if (node < NNODES) {
                unsigned us = hp[(size_t)node * 64 + lane];
                float ax = bf2f_lo(us), ay = bf2f_hi(us);
                const int s = row_off[node];
                const int e = s + cntA[node];
                int j = s;
                for (; j + 3 < e; j += 4) {
                    int u0 = col[j], u1 = col[j + 1], u2 = col[j + 2], u3 = col[j + 3];
                    unsigned v0 = hp[(size_t)u0 * 64 + lane];
                    unsigned v1 = hp[(size_t)u1 * 64 + lane];
                    unsigned v2 = hp[(size_t)u2 * 64 + lane];
                    unsigned v3 = hp[(size_t)u3 * 64 + lane];
                    ax += bf2f_lo(v0) + bf2f_lo(v1) + bf2f_lo(v2) + bf2f_lo(v3);
                    ay += bf2f_hi(v0) + bf2f_hi(v1) + bf2f_hi(v2) + bf2f_hi(v3);
                }
                for (; j < e; ++j) {
                    unsigned v = hp[(size_t)col[j] * 64 + lane];
                    ax += bf2f_lo(v); ay += bf2f_hi(v);
                }
                const float scv = inv[node];
                float ox = fmaxf(fmaf(ax, scv, bb.x), 0.f);
                float oy = fmaxf(fmaf(ay, scv, bb.y), 0.f);
                packed = (unsigned)(unsigned short)f2bf(ox) |
                         ((unsigned)(unsigned short)f2bf(oy) << 16);
            }
            *(unsigned*)&As[(wave * 16 + i) * LDA + lane * 2] = packed;
        }
    }
    __syncthreads();

    // ---- GEMM phase: one 16-row m-tile per wave
    const int ml = lane & 15, quad = lane >> 4;
    const int w16 = wave * 16;

    f32x4 acc[8] = {};
    #pragma unroll
    for (int kk = 0; kk < 4; ++kk) {
        const int k0 = kk * 32 + quad * 8;
        bf16x8 a = *(bf16x8*)&As[(w16 + ml) * LDA + k0];
        #pragma unroll
        for (int ni = 0; ni < 8; ++ni) {
            bf16x8 b = *(bf16x8*)&Bs[(ni * 16 + ml) * LDA + k0];
            acc[ni] = __builtin_amdgcn_mfma_f32_16x16x32_bf16(a, b, acc[ni], 0, 0, 0);
        }
    }
    // epilogue *inv[row] -> wave-local As rows -> coalesced store
    #pragma unroll
    for (int ni = 0; ni < 8; ++ni) {
        const int colc = ni * 16 + ml;
        #pragma unroll
        for (int r = 0; r < 4; ++r) {
            const int rowl = w16 + quad * 4 + r;
            float v = acc[ni][r] * inv[min(m0 + rowl, NNODES - 1)];
            As[rowl * LDA + colc] = f2bf(v);
        }
    }
    const int srow = w16 + (lane >> 2), sch = (lane & 3) * 32;
    const int grow = m0 + srow;
    if (grow < NNODES) {
        #pragma unroll
        for (int c = 0; c < 4; ++c)
            *(bf16x8*)(hw_out + (size_t)grow * DIM + sch + c * 8) =
                *(bf16x8*)&As[srow * LDA + sch + c * 8];
    }
}

// ============================================================
// Fused agg + global-add-pool: h3 = relu(inv*(hw2[n]+sum)+b2) summed into
// pooled[batch[n]] via segmented fp32 atomics (batch sorted).
// ============================================================
__global__ __launch_bounds__(512, 8) void k_aggpool(
    const short* __restrict__ hw_in, const int* __restrict__ row_off,
    const int* __restrict__ cntA, const int* __restrict__ col,
    const float* __restrict__ inv, const float* __restrict__ bias,
    const int* __restrict__ batch, float* __restrict__ pooled)
{
    const int tid = threadIdx.x;
    const int wave = tid >> 6, lane = tid & 63;
    const int node0 = blockIdx.x * 128 + wave * 16;
    const unsigned* hp = (const unsigned*)hw_in;
    const float2 bb = ((const float2*)bias)[lane];

    float gx = 0.f, gy = 0.f;
    int cg = -1;
    #pragma unroll 1
    for (int i = 0; i < 16; ++i) {
        const int node = node0 + i;
        if (node >= NNODES) break;
        const int g = batch[node];
        if (g != cg) {
            if (cg >= 0) {
                atomicAdd(pooled + (size_t)cg * DIM + lane * 2,     gx);
                atomicAdd(pooled + (size_t)cg * DIM + lane * 2 + 1, gy);
            }
            cg = g; gx = 0.f; gy = 0.f;
        }
        unsigned us = hp[(size_t)node * 64 + lane];
        float ax = bf2f_lo(us), ay = bf2f_hi(us);
        const int s = row_off[node];
        const int e = s + cntA[node];
        int j = s;
        for (; j + 3 < e; j += 4) {
            int u0 = col[j], u1 = col[j + 1], u2 = col[j + 2], u3 = col[j + 3];
            unsigned v0 = hp[(size_t)u0 * 64 + lane];
            unsigned v1 = hp[(size_t)u1 * 64 + lane];
            unsigned v2 = hp[(size_t)u2 * 64 + lane];
            unsigned v3 = hp[(size_t)u3 * 64 + lane];
            ax += bf2f_lo(v0) + bf2f_lo(v1) + bf2f_lo(v2) + bf2f_lo(v3);
            ay += bf2f_hi(v0) + bf2f_hi(v1) + bf2f_hi(v2) + bf2f_hi(v3);
        }
        for (; j < e; ++j) {
            unsigned v = hp[(size_t)col[j] * 64 + lane];
            ax += bf2f_lo(v); ay += bf2f_hi(v);
        }
        const float scv = inv[node];
        gx += fmaxf(fmaf(ax, scv, bb.x), 0.f);
        gy += fmaxf(fmaf(ay, scv, bb.y), 0.f);
    }
    if (cg >= 0) {
        atomicAdd(pooled + (size_t)cg * DIM + lane * 2,     gx);
        atomicAdd(pooled + (size_t)cg * DIM + lane * 2 + 1, gy);
    }
}

// ============================================================
// CSR build (unchanged from round 4) + init
// ============================================================
__global__ __launch_bounds__(256) void k_init(int* __restrict__ gcur,
                                              float* __restrict__ pooled) {
    int i = blockIdx.x * 256 + threadIdx.x;
    if (i < NBUCK2) gcur[i] = i * CAP;
    if (i < NGRAPH * DIM) pooled[i] = 0.f;
}

__global__ __launch_bounds__(512) void k_scatter(
    const int* __restrict__ src, const int* __restrict__ dst,
    int* __restrict__ gcur, unsigned* __restrict__ tmp)
{
    __shared__ unsigned short rnk[EPB2];
    __shared__ int h[NBUCK2];
    __shared__ int gbase[NBUCK2];
    const int tid  = threadIdx.x;
    const int base = blockIdx.x * EPB2;
    if (tid < NBUCK2) h[tid] = 0;
    __syncthreads();
    #pragma unroll
    for (int it = 0; it < EPB2 / 512; ++it) {
        int e = base + it * 512 + tid;
        if (e < NEDGES) {
            int b = dst[e] >> BSHIFT;
            rnk[it * 512 + tid] = (unsigned short)atomicAdd(&h[b], 1);
        }
    }
    __syncthreads();
    if (tid < NBUCK2 && h[tid] > 0)
        gbase[tid] = atomicAdd(&gcur[tid], h[tid]);
    __syncthreads();
    #pragma unroll
    for (int it = 0; it < EPB2 / 512; ++it) {
        int e = base + it * 512 + tid;
        if (e < NEDGES) {
            int d = dst[e], sv = src[e];
            int b = d >> BSHIFT;
            int pos = gbase[b] + rnk[it * 512 + tid];
            if (pos < (b + 1) * CAP)
                tmp[pos] = (unsigned)sv | ((unsigned)(d & 511) << 17);
        }
    }
}

__global__ __launch_bounds__(512) void k_build(
    const unsigned* __restrict__ tmp, const int* __restrict__ gcur,
    int* __restrict__ row_off, int* __restrict__ cntA,
    float* __restrict__ inv, int* __restrict__ col)
{
    __shared__ int hist[512], sc[512], lcur[512];
    const int tid   = threadIdx.x;
    const int b     = blockIdx.x;
    const int tbase = b * CAP;
    const int cnt_b = min(gcur[b] - tbase, CAP);
    hist[tid] = 0;
    __syncthreads();
    for (int i = tid; i < cnt_b; i += 512)
        atomicAdd(&hist[(tmp[tbase + i] >> 17) & 511], 1);
    __syncthreads();
    const int hv = hist[tid];
    sc[tid] = hv;
    __syncthreads();
    for (int off = 1; off < 512; off <<= 1) {
        int t = (tid >= off) ? sc[tid - off] : 0;
        __syncthreads();
        sc[tid] += t;
        __syncthreads();
    }
    const int start = tbase + sc[tid] - hv;
    lcur[tid] = start;
    const int node = b * 512 + tid;
    if (node < NNODES) {
        row_off[node] = start;
        cntA[node]    = hv;
        inv[node]     = rsqrtf((float)hv + 1.0f);
    }
    __syncthreads();
    for (int i = tid; i < cnt_b; i += 512) {
        unsigned t = tmp[tbase + i];
        int pos = atomicAdd(&lcur[(t >> 17) & 511], 1);
        col[pos] = (int)(t & 0x1FFFFu);
    }
}

// ============================================================
// Decoder (fp32, tiny)
// ============================================================
__global__ __launch_bounds__(256) void gemm128_f32(
    const float* __restrict__ A, const float* __restrict__ W,
    const float* __restrict__ bias, float* __restrict__ C, int M)
{
    __shared__ float As[16][132];
    __shared__ float Bs[16][132];

    const int tid = threadIdx.x;
    const int m0  = blockIdx.x * 128;
    const int tx  = tid & 15;
    const int ty  = tid >> 4;
    const int ar = tid >> 2;
    const int ac = (tid & 3) << 2;
    const int br = tid >> 5;
    const int bc = (tid & 31) << 2;

    float acc[8][8];
    #pragma unroll
    for (int i = 0; i < 8; ++i)
        #pragma unroll
        for (int j = 0; j < 8; ++j) acc[i][j] = 0.f;

    for (int kt = 0; kt < 8; ++kt) {
        const int k0 = kt << 4;
        const int r0 = min(m0 + ar,      M - 1);
        const int r1 = min(m0 + ar + 64, M - 1);
        float4 a0 = *(const float4*)(A + (size_t)r0 * DIM + k0 + ac);
        float4 a1 = *(const float4*)(A + (size_t)r1 * DIM + k0 + ac);
        float4 b0 = *(const float4*)(W + (size_t)(k0 + br)     * DIM + bc);
        float4 b1 = *(const float4*)(W + (size_t)(k0 + br + 8) * DIM + bc);

        __syncthreads();
        As[ac + 0][ar] = a0.x; As[ac + 1][ar] = a0.y;
        As[ac + 2][ar] = a0.z; As[ac + 3][ar] = a0.w;
        As[ac + 0][ar + 64] = a1.x; As[ac + 1][ar + 64] = a1.y;
        As[ac + 2][ar + 64] = a1.z; As[ac + 3][ar + 64] = a1.w;
        *(float4*)&Bs[br][bc]     = b0;
        *(float4*)&Bs[br + 8][bc] = b1;
        __syncthreads();

        #pragma unroll
        for (int kk = 0; kk < 16; ++kk) {
            float4 fa0 = *(const float4*)&As[kk][ty * 8];
            float4 fa1 = *(const float4*)&As[kk][ty * 8 + 4];
            float4 fb0 = *(const float4*)&Bs[kk][tx * 8];
            float4 fb1 = *(const float4*)&Bs[kk][tx * 8 + 4];
            float av[8] = {fa0.x, fa0.y, fa0.z, fa0.w, fa1.x, fa1.y, fa1.z, fa1.w};
            float bv[8] = {fb0.x, fb0.y, fb0.z, fb0.w, fb1.x, fb1.y, fb1.z, fb1.w};
            #pragma unroll
            for (int i = 0; i < 8; ++i)
                #pragma unroll
                for (int j = 0; j < 8; ++j)
                    acc[i][j] = fmaf(av[i], bv[j], acc[i][j]);
        }
    }

    float4 bb0 = *(const float4*)(bias + tx * 8);
    float4 bb1 = *(const float4*)(bias + tx * 8 + 4);
    float bcol[8] = {bb0.x, bb0.y, bb0.z, bb0.w, bb1.x, bb1.y, bb1.z, bb1.w};

    #pragma unroll
    for (int i = 0; i < 8; ++i) {
        const int r = m0 + ty * 8 + i;
        if (r >= M) break;
        float v[8];
        #pragma unroll
        for (int j = 0; j < 8; ++j) v[j] = fmaxf(acc[i][j] + bcol[j], 0.f);
        *(float4*)(C + (size_t)r * DIM + tx * 8)     = make_float4(v[0], v[1], v[2], v[3]);
        *(float4*)(C + (size_t)r * DIM + tx * 8 + 4) = make_float4(v[4], v[5], v[6], v[7]);
    }
}

__global__ __launch_bounds__(256) void k_dec2(
    const float* __restrict__ t1, const float* __restrict__ W2,
    const float* __restrict__ b2, float* __restrict__ out)
{
    int idx = blockIdx.x * 256 + threadIdx.x;
    if (idx >= NGRAPH * OUTD) return;
    int r = idx >> 5, c = idx & 31;
    float acc = b2[c];
    #pragma unroll 8
    for (int k = 0; k < DIM; ++k)
        acc = fmaf(t1[(size_t)r * DIM + k], W2[(size_t)k * OUTD + c], acc);
    out[idx] = acc;
}

// ============================================================
extern "C" void kernel_launch(void* const* d_in, const int* in_sizes, int n_in,
                              void* d_out, int out_size, void* d_ws, size_t ws_size,
                              hipStream_t stream)
{
    const float* x      = (const float*)d_in[0];
    const int*   ei     = (const int*)d_in[1];
    const int*   batch  = (const int*)d_in[2];
    const float* enc_W1 = (const float*)d_in[3];
    const float* enc_b1 = (const float*)d_in[4];
    const float* enc_W2 = (const float*)d_in[5];
    const float* enc_b2 = (const float*)d_in[6];
    const float* gcn_W  = (const float*)d_in[7];
    const float* gcn_b  = (const float*)d_in[8];
    const float* dec_W1 = (const float*)d_in[9];
    const float* dec_b1 = (const float*)d_in[10];
    const float* dec_W2 = (const float*)d_in[11];
    const float* dec_b2 = (const float*)d_in[12];
    float* out = (float*)d_out;

    const int* src = ei;
    const int* dst = ei + NEDGES;

    char* p = (char*)d_ws;
    auto alloc = [&](size_t bytes) -> void* {
        void* r = (void*)p;
        p += (bytes + 255) & ~(size_t)255;
        return r;
    };
    short*    hwA    = (short*)   alloc((size_t)NNODES * DIM * sizeof(short));
    short*    hwB    = (short*)   alloc((size_t)NNODES * DIM * sizeof(short));
    float*    inv    = (float*)   alloc((size_t)NNODES * sizeof(float));
    int*      row_off= (int*)     alloc((size_t)NNODES * sizeof(int));
    int*      cntA   = (int*)     alloc((size_t)NNODES * sizeof(int));
    int*      col    = (int*)     alloc((size_t)NBUCK2 * CAP * sizeof(int));
    unsigned* tmp    = (unsigned*)alloc((size_t)NBUCK2 * CAP * sizeof(unsigned));
    int*      gcur   = (int*)     alloc((size_t)NBUCK2 * sizeof(int));
    short*    WT     = (short*)   alloc((size_t)5 * DIM * DIM * sizeof(short));
    float*    pooled = (float*)   alloc((size_t)NGRAPH * DIM * sizeof(float));
    float*    t1     = (float*)   alloc((size_t)NGRAPH * DIM * sizeof(float));

    // ---- init + CSR build ----
    k_init   <<<(NGRAPH * DIM + 255) / 256, 256, 0, stream>>>(gcur, pooled);
    k_scatter<<<SBLOCKS, 512, 0, stream>>>(src, dst, gcur, tmp);
    k_build  <<<NBUILD, 512, 0, stream>>>(tmp, gcur, row_off, cntA, inv, col);

    // ---- weight pre-transpose: WT = [enc_W1, enc_W2, gcn_W0, gcn_W1, gcn_W2]
    k_prepW<<<(DIM * DIM + 255) / 256, 256, 0, stream>>>(enc_W1, WT, 1);
    k_prepW<<<(DIM * DIM + 255) / 256, 256, 0, stream>>>(enc_W2, WT + 16384, 1);
    k_prepW<<<(3 * DIM * DIM + 255) / 256, 256, 0, stream>>>(gcn_W, WT + 2 * 16384, 3);

    // ---- fused pipeline ----
    k_enc    <<<FBLOCKS, 512, 0, stream>>>(x, WT, enc_b1, enc_b2, inv, hwA, NNODES);
    k_agggemm<<<FBLOCKS, 512, 0, stream>>>(hwA, row_off, cntA, col, inv,
                                           gcn_b,       WT + 3 * 16384, hwB);
    k_agggemm<<<FBLOCKS, 512, 0, stream>>>(hwB, row_off, cntA, col, inv,
                                           gcn_b + 128, WT + 4 * 16384, hwA);
    k_aggpool<<<FBLOCKS, 512, 0, stream>>>(hwA, row_off, cntA, col, inv,
                                           gcn_b + 256, batch, pooled);

    // ---- decoder ----
    gemm128_f32<<<(NGRAPH + 127) / 128, 256, 0, stream>>>(pooled, dec_W1, dec_b1, t1, NGRAPH);
    k_dec2<<<(NGRAPH * OUTD + 255) / 256, 256, 0, stream>>>(t1, dec_W2, dec_b2, out);
}

// Round 6
// 496.633 us; speedup vs baseline: 1.1901x; 1.1901x over previous
//
#include <hip/hip_runtime.h>

#define NNODES 100000
#define NEDGES 1600000
#define DIM    128
#define OUTD   32
#define NGRAPH 512
#define LDA    136   // padded LDS stride (bf16 elems)

#define NBUCK2  256                          // coarse buckets: dst >> 9
#define BSHIFT  9
#define CAP     12288                        // per-bucket region capacity (mean 8163)
#define EPB2    8192
#define SBLOCKS ((NEDGES + EPB2 - 1) / EPB2) // 196
#define NBUILD  ((NNODES + 511) / 512)       // 196
#define FBLOCKS ((NNODES + 127) / 128)       // 782

using bf16x8 = __attribute__((ext_vector_type(8))) short;
using f32x4  = __attribute__((ext_vector_type(4))) float;

__device__ __forceinline__ short f2bf(float f) {
    unsigned u = __float_as_uint(f);
    unsigned r = (u + 0x7fff + ((u >> 16) & 1)) >> 16;   // RNE
    return (short)r;
}
__device__ __forceinline__ float bf2f(short s) {
    return __uint_as_float(((unsigned)(unsigned short)s) << 16);
}
__device__ __forceinline__ float bf2f_lo(unsigned u) { return __uint_as_float(u << 16); }
__device__ __forceinline__ float bf2f_hi(unsigned u) { return __uint_as_float(u & 0xffff0000u); }

// ============================================================
// Weight pre-transpose: WT[mat][n][k] = bf16(W[mat][k][n])
// ============================================================
__global__ __launch_bounds__(256) void k_prepW(
    const float* __restrict__ W, short* __restrict__ WT, int nmat)
{
    int idx = blockIdx.x * 256 + threadIdx.x;
    if (idx >= nmat * DIM * DIM) return;
    int mat = idx >> 14;
    int rem = idx & 16383;
    int k = rem >> 7, n = rem & 127;
    WT[(size_t)mat * 16384 + n * DIM + k] = f2bf(W[(size_t)mat * 16384 + k * DIM + n]);
}

// ============================================================
// Fused encoder: x -> relu(xW1+b1) -> relu(..W2+b2) -> (..Wg0)*inv -> hw0
// 512 thr / 128 rows per block. Three chained MFMA GEMMs, h in LDS.
// ============================================================
__global__ __launch_bounds__(512, 4) void k_enc(
    const float* __restrict__ x, const short* __restrict__ WT,
    const float* __restrict__ b1, const float* __restrict__ b2,
    const float* __restrict__ inv, short* __restrict__ hw0, int M)
{
    __shared__ short As[128 * LDA];
    __shared__ short Bs[128 * LDA];

    const int tid = threadIdx.x;
    const int m0  = blockIdx.x * 128;

    // ---- stage x (fp32 -> bf16)
    {
        const int row = tid >> 2, ch = (tid & 3) * 32;
        const int gr  = min(m0 + row, M - 1);
        const float4* sp = (const float4*)(x + (size_t)gr * DIM + ch);
        #pragma unroll
        for (int c = 0; c < 4; ++c) {
            float4 f0 = sp[c * 2], f1 = sp[c * 2 + 1];
            short t8[8] = { f2bf(f0.x), f2bf(f0.y), f2bf(f0.z), f2bf(f0.w),
                            f2bf(f1.x), f2bf(f1.y), f2bf(f1.z), f2bf(f1.w) };
            *(bf16x8*)&As[row * LDA + ch + c * 8] = *(bf16x8*)t8;
        }
    }

    const int wave = tid >> 6, lane = tid & 63;
    const int ml = lane & 15, quad = lane >> 4;
    const int w16 = wave * 16;
    const int brow = tid >> 2, bch = (tid & 3) * 32;

    #pragma unroll
    for (int mat = 0; mat < 3; ++mat) {
        if (mat > 0) __syncthreads();
        const short* wt = WT + (size_t)mat * 16384 + brow * DIM + bch;
        #pragma unroll
        for (int c = 0; c < 4; ++c)
            *(bf16x8*)&Bs[brow * LDA + bch + c * 8] = *(const bf16x8*)(wt + c * 8);
        __syncthreads();

        f32x4 acc[8] = {};
        #pragma unroll
        for (int kk = 0; kk < 4; ++kk) {
            const int k0 = kk * 32 + quad * 8;
            bf16x8 a = *(bf16x8*)&As[(w16 + ml) * LDA + k0];
            #pragma unroll
            for (int ni = 0; ni < 8; ++ni) {
                bf16x8 b = *(bf16x8*)&Bs[(ni * 16 + ml) * LDA + k0];
                acc[ni] = __builtin_amdgcn_mfma_f32_16x16x32_bf16(a, b, acc[ni], 0, 0, 0);
            }
        }
        #pragma unroll
        for (int ni = 0; ni < 8; ++ni) {
            const int colc = ni * 16 + ml;
            #pragma unroll
            for (int r = 0; r < 4; ++r) {
                const int rowl = w16 + quad * 4 + r;
                float v = acc[ni][r];
                if (mat == 0)      v = fmaxf(v + b1[colc], 0.f);
                else if (mat == 1) v = fmaxf(v + b2[colc], 0.f);
                else               v *= inv[min(m0 + rowl, M - 1)];
                As[rowl * LDA + colc] = f2bf(v);
            }
        }
    }

    const int srow = w16 + (lane >> 2), sch = (lane & 3) * 32;
    const int grow = m0 + srow;
    if (grow < M) {
        #pragma unroll
        for (int c = 0; c < 4; ++c)
            *(bf16x8*)(hw0 + (size_t)grow * DIM + sch + c * 8) =
                *(bf16x8*)&As[srow * LDA + sch + c * 8];
    }
}

// ============================================================
// bf16 MFMA GEMM (GCN layers): C = (A @ W)*inv[row], W as bf16 W^T
// ============================================================
__global__ __launch_bounds__(256) void gemm_mfma(
    const short* __restrict__ A, const short* __restrict__ WT,
    const float* __restrict__ inv, short* __restrict__ C, int M)
{
    __shared__ short As[128 * LDA];
    __shared__ short Bs[128 * LDA];

    const int tid = threadIdx.x;
    const int m0  = blockIdx.x * 128;

    #pragma unroll
    for (int i = 0; i < 8; ++i) {
        int idx = tid + i * 256;
        int row = idx >> 4, kg = (idx & 15) << 3;
        int r = min(m0 + row, M - 1);
        *(bf16x8*)&As[row * LDA + kg] = *(const bf16x8*)(A + (size_t)r * DIM + kg);
    }
    #pragma unroll
    for (int i = 0; i < 8; ++i) {
        int idx = tid + i * 256;
        int n = idx >> 4, kg = (idx & 15) << 3;
        *(bf16x8*)&Bs[n * LDA + kg] = *(const bf16x8*)(WT + n * DIM + kg);
    }
    __syncthreads();

    const int wave = tid >> 6, lane = tid & 63;
    const int ml = lane & 15, quad = lane >> 4;
    const int w32 = wave * 32;

    f32x4 acc[2][8] = {};
    #pragma unroll
    for (int kk = 0; kk < 4; ++kk) {
        const int k0 = kk * 32 + quad * 8;
        bf16x8 a0 = *(bf16x8*)&As[(w32 + ml) * LDA + k0];
        bf16x8 a1 = *(bf16x8*)&As[(w32 + 16 + ml) * LDA + k0];
        #pragma unroll
        for (int ni = 0; ni < 8; ++ni) {
            bf16x8 b = *(bf16x8*)&Bs[(ni * 16 + ml) * LDA + k0];
            acc[0][ni] = __builtin_amdgcn_mfma_f32_16x16x32_bf16(a0, b, acc[0][ni], 0, 0, 0);
            acc[1][ni] = __builtin_amdgcn_mfma_f32_16x16x32_bf16(a1, b, acc[1][ni], 0, 0, 0);
        }
    }
    __syncthreads();

    short* Cs = As;
    #pragma unroll
    for (int mi = 0; mi < 2; ++mi) {
        #pragma unroll
        for (int ni = 0; ni < 8; ++ni) {
            const int colc = ni * 16 + ml;
            #pragma unroll
            for (int r = 0; r < 4; ++r) {
                const int row = w32 + mi * 16 + quad * 4 + r;
                float v = acc[mi][ni][r] * inv[min(m0 + row, M - 1)];
                Cs[row * LDA + colc] = f2bf(v);
            }
        }
    }
    __syncthreads();
    #pragma unroll
    for (int i = 0; i < 8; ++i) {
        int idx = tid + i * 256;
        int row = idx >> 4, cg = (idx & 15) << 3;
        int gr = m0 + row;
        if (gr < M)
            *(bf16x8*)(C + (size_t)gr * DIM + cg) = *(bf16x8*)&Cs[row * LDA + cg];
    }
}

// ============================================================
// Aggregation v2: 2 nodes per wave, 32 lanes x uint2 (8B) per node.
// h_out[n] = relu(inv[n]*(hw'[n] + sum hw'[src]) + bias)
// ============================================================
__global__ __launch_bounds__(512) void k_agg(
    const short* __restrict__ hwp, const int* __restrict__ row_off,
    const int* __restrict__ cntA, const int* __restrict__ col,
    const float* __restrict__ inv, const float* __restrict__ bias,
    short* __restrict__ hout)
{
    const int wid  = blockIdx.x * 8 + (threadIdx.x >> 6);
    const int lane = threadIdx.x & 63;
    const int half = lane >> 5;
    const int sl   = lane & 31;
    const int node = wid * 2 + half;
    if (node >= NNODES) return;

    const uint2* hp = (const uint2*)hwp;   // 8 B = 4 bf16 feats
    uint2 us = hp[(size_t)node * 32 + sl];
    float a0 = bf2f_lo(us.x), a1 = bf2f_hi(us.x);
    float a2 = bf2f_lo(us.y), a3 = bf2f_hi(us.y);

    const int s = row_off[node];
    const int e = s + cntA[node];
    int j = s;
    for (; j + 3 < e; j += 4) {
        int u0 = col[j], u1 = col[j + 1], u2 = col[j + 2], u3 = col[j + 3];
        uint2 v0 = hp[(size_t)u0 * 32 + sl];
        uint2 v1 = hp[(size_t)u1 * 32 + sl];
        uint2 v2 = hp[(size_t)u2 * 32 + sl];
        uint2 v3 = hp[(size_t)u3 * 32 + sl];
        a0 += bf2f_lo(v0.x) + bf2f_lo(v1.x) + bf2f_lo(v2.x) + bf2f_lo(v3.x);
        a1 += bf2f_hi(v0.x) + bf2f_hi(v1.x) + bf2f_hi(v2.x) + bf2f_hi(v3.x);
        a2 += bf2f_lo(v0.y) + bf2f_lo(v1.y) + bf2f_lo(v2.y) + bf2f_lo(v3.y);
        a3 += bf2f_hi(v0.y) + bf2f_hi(v1.y) + bf2f_hi(v2.y) + bf2f_hi(v3.y);
    }
    for (; j < e; ++j) {
        uint2 v = hp[(size_t)col[j] * 32 + sl];
        a0 += bf2f_lo(v.x); a1 += bf2f_hi(v.x);
        a2 += bf2f_lo(v.y); a3 += bf2f_hi(v.y);
    }
    const float scv = inv[node];
    const float4 bb = ((const float4*)bias)[sl];
    float o0 = fmaxf(fmaf(a0, scv, bb.x), 0.f);
    float o1 = fmaxf(fmaf(a1, scv, bb.y), 0.f);
    float o2 = fmaxf(fmaf(a2, scv, bb.z), 0.f);
    float o3 = fmaxf(fmaf(a3, scv, bb.w), 0.f);
    uint2 o;
    o.x = (unsigned)(unsigned short)f2bf(o0) | ((unsigned)(unsigned short)f2bf(o1) << 16);
    o.y = (unsigned)(unsigned short)f2bf(o2) | ((unsigned)(unsigned short)f2bf(o3) << 16);
    ((uint2*)hout)[(size_t)node * 32 + sl] = o;
}

// ============================================================
// CSR build + init
// ============================================================
__global__ __launch_bounds__(256) void k_init(int* __restrict__ gcur) {
    int i = blockIdx.x * 256 + threadIdx.x;
    if (i < NBUCK2) gcur[i] = i * CAP;
}

__global__ __launch_bounds__(512) void k_scatter(
    const int* __restrict__ src, const int* __restrict__ dst,
    int* __restrict__ gcur, unsigned* __restrict__ tmp)
{
    __shared__ unsigned short rnk[EPB2];
    __shared__ int h[NBUCK2];
    __shared__ int gbase[NBUCK2];
    const int tid  = threadIdx.x;
    const int base = blockIdx.x * EPB2;
    if (tid < NBUCK2) h[tid] = 0;
    __syncthreads();
    #pragma unroll
    for (int it = 0; it < EPB2 / 512; ++it) {
        int e = base + it * 512 + tid;
        if (e < NEDGES) {
            int b = dst[e] >> BSHIFT;
            rnk[it * 512 + tid] = (unsigned short)atomicAdd(&h[b], 1);
        }
    }
    __syncthreads();
    if (tid < NBUCK2 && h[tid] > 0)
        gbase[tid] = atomicAdd(&gcur[tid], h[tid]);
    __syncthreads();
    #pragma unroll
    for (int it = 0; it < EPB2 / 512; ++it) {
        int e = base + it * 512 + tid;
        if (e < NEDGES) {
            int d = dst[e], sv = src[e];
            int b = d >> BSHIFT;
            int pos = gbase[b] + rnk[it * 512 + tid];
            if (pos < (b + 1) * CAP)
                tmp[pos] = (unsigned)sv | ((unsigned)(d & 511) << 17);
        }
    }
}

__global__ __launch_bounds__(512) void k_build(
    const unsigned* __restrict__ tmp, const int* __restrict__ gcur,
    int* __restrict__ row_off, int* __restrict__ cntA,
    float* __restrict__ inv, int* __restrict__ col)
{
    __shared__ int hist[512], sc[512], lcur[512];
    const int tid   = threadIdx.x;
    const int b     = blockIdx.x;
    const int tbase = b * CAP;
    const int cnt_b = min(gcur[b] - tbase, CAP);
    hist[tid] = 0;
    __syncthreads();
    for (int i = tid; i < cnt_b; i += 512)
        atomicAdd(&hist[(tmp[tbase + i] >> 17) & 511], 1);
    __syncthreads();
    const int hv = hist[tid];
    sc[tid] = hv;
    __syncthreads();
    for (int off = 1; off < 512; off <<= 1) {
        int t = (tid >= off) ? sc[tid - off] : 0;
        __syncthreads();
        sc[tid] += t;
        __syncthreads();
    }
    const int start = tbase + sc[tid] - hv;
    lcur[tid] = start;
    const int node = b * 512 + tid;
    if (node < NNODES) {
        row_off[node] = start;
        cntA[node]    = hv;
        inv[node]     = rsqrtf((float)hv + 1.0f);
    }
    __syncthreads();
    for (int i = tid; i < cnt_b; i += 512) {
        unsigned t = tmp[tbase + i];
        int pos = atomicAdd(&lcur[(t >> 17) & 511], 1);
        col[pos] = (int)(t & 0x1FFFFu);
    }
}

// ============================================================
// Global add pool (bf16 in, fp32 out)
// ============================================================
__device__ int lbound(const int* __restrict__ a, int n, int v) {
    int lo = 0, hi = n;
    while (lo < hi) { int mid = (lo + hi) >> 1; if (a[mid] < v) lo = mid + 1; else hi = mid; }
    return lo;
}

__global__ __launch_bounds__(128) void k_pool(
    const short* __restrict__ h, const int* __restrict__ batch,
    float* __restrict__ pooled)
{
    __shared__ int se[2];
    const int g = blockIdx.x;
    if (threadIdx.x == 0) se[0] = lbound(batch, NNODES, g);
    if (threadIdx.x == 1) se[1] = lbound(batch, NNODES, g + 1);
    __syncthreads();
    const int s = se[0], e = se[1];
    const int f = threadIdx.x;
    float acc = 0.f;
    for (int n = s; n < e; ++n) acc += bf2f(h[(size_t)n * DIM + f]);
    pooled[(size_t)g * DIM + f] = acc;
}

// ============================================================
// Decoder (fp32, tiny)
// ============================================================
__global__ __launch_bounds__(256) void gemm128_f32(
    const float* __restrict__ A, const float* __restrict__ W,
    const float* __restrict__ bias, float* __restrict__ C, int M)
{
    __shared__ float As[16][132];
    __shared__ float Bs[16][132];

    const int tid = threadIdx.x;
    const int m0  = blockIdx.x * 128;
    const int tx  = tid & 15;
    const int ty  = tid >> 4;
    const int ar = tid >> 2;
    const int ac = (tid & 3) << 2;
    const int br = tid >> 5;
    const int bc = (tid & 31) << 2;

    float acc[8][8];
    #pragma unroll
    for (int i = 0; i < 8; ++i)
        #pragma unroll
        for (int j = 0; j < 8; ++j) acc[i][j] = 0.f;

    for (int kt = 0; kt < 8; ++kt) {
        const int k0 = kt << 4;
        const int r0 = min(m0 + ar,      M - 1);
        const int r1 = min(m0 + ar + 64, M - 1);
        float4 a0 = *(const float4*)(A + (size_t)r0 * DIM + k0 + ac);
        float4 a1 = *(const float4*)(A + (size_t)r1 * DIM + k0 + ac);
        float4 b0 = *(const float4*)(W + (size_t)(k0 + br)     * DIM + bc);
        float4 b1 = *(const float4*)(W + (size_t)(k0 + br + 8) * DIM + bc);

        __syncthreads();
        As[ac + 0][ar] = a0.x; As[ac + 1][ar] = a0.y;
        As[ac + 2][ar] = a0.z; As[ac + 3][ar] = a0.w;
        As[ac + 0][ar + 64] = a1.x; As[ac + 1][ar + 64] = a1.y;
        As[ac + 2][ar + 64] = a1.z; As[ac + 3][ar + 64] = a1.w;
        *(float4*)&Bs[br][bc]     = b0;
        *(float4*)&Bs[br + 8][bc] = b1;
        __syncthreads();

        #pragma unroll
        for (int kk = 0; kk < 16; ++kk) {
            float4 fa0 = *(const float4*)&As[kk][ty * 8];
            float4 fa1 = *(const float4*)&As[kk][ty * 8 + 4];
            float4 fb0 = *(const float4*)&Bs[kk][tx * 8];
            float4 fb1 = *(const float4*)&Bs[kk][tx * 8 + 4];
            float av[8] = {fa0.x, fa0.y, fa0.z, fa0.w, fa1.x, fa1.y, fa1.z, fa1.w};
            float bv[8] = {fb0.x, fb0.y, fb0.z, fb0.w, fb1.x, fb1.y, fb1.z, fb1.w};
            #pragma unroll
            for (int i = 0; i < 8; ++i)
                #pragma unroll
                for (int j = 0; j < 8; ++j)
                    acc[i][j] = fmaf(av[i], bv[j], acc[i][j]);
        }
    }

    float4 bb0 = *(const float4*)(bias + tx * 8);
    float4 bb1 = *(const float4*)(bias + tx * 8 + 4);
    float bcol[8] = {bb0.x, bb0.y, bb0.z, bb0.w, bb1.x, bb1.y, bb1.z, bb1.w};

    #pragma unroll
    for (int i = 0; i < 8; ++i) {
        const int r = m0 + ty * 8 + i;
        if (r >= M) break;
        float v[8];
        #pragma unroll
        for (int j = 0; j < 8; ++j) v[j] = fmaxf(acc[i][j] + bcol[j], 0.f);
        *(float4*)(C + (size_t)r * DIM + tx * 8)     = make_float4(v[0], v[1], v[2], v[3]);
        *(float4*)(C + (size_t)r * DIM + tx * 8 + 4) = make_float4(v[4], v[5], v[6], v[7]);
    }
}

__global__ __launch_bounds__(256) void k_dec2(
    const float* __restrict__ t1, const float* __restrict__ W2,
    const float* __restrict__ b2, float* __restrict__ out)
{
    int idx = blockIdx.x * 256 + threadIdx.x;
    if (idx >= NGRAPH * OUTD) return;
    int r = idx >> 5, c = idx & 31;
    float acc = b2[c];
    #pragma unroll 8
    for (int k = 0; k < DIM; ++k)
        acc = fmaf(t1[(size_t)r * DIM + k], W2[(size_t)k * OUTD + c], acc);
    out[idx] = acc;
}

// ============================================================
extern "C" void kernel_launch(void* const* d_in, const int* in_sizes, int n_in,
                              void* d_out, int out_size, void* d_ws, size_t ws_size,
                              hipStream_t stream)
{
    const float* x      = (const float*)d_in[0];
    const int*   ei     = (const int*)d_in[1];
    const int*   batch  = (const int*)d_in[2];
    const float* enc_W1 = (const float*)d_in[3];
    const float* enc_b1 = (const float*)d_in[4];
    const float* enc_W2 = (const float*)d_in[5];
    const float* enc_b2 = (const float*)d_in[6];
    const float* gcn_W  = (const float*)d_in[7];
    const float* gcn_b  = (const float*)d_in[8];
    const float* dec_W1 = (const float*)d_in[9];
    const float* dec_b1 = (const float*)d_in[10];
    const float* dec_W2 = (const float*)d_in[11];
    const float* dec_b2 = (const float*)d_in[12];
    float* out = (float*)d_out;

    const int* src = ei;
    const int* dst = ei + NEDGES;

    char* p = (char*)d_ws;
    auto alloc = [&](size_t bytes) -> void* {
        void* r = (void*)p;
        p += (bytes + 255) & ~(size_t)255;
        return r;
    };
    short*    hwA    = (short*)   alloc((size_t)NNODES * DIM * sizeof(short));
    short*    hwB    = (short*)   alloc((size_t)NNODES * DIM * sizeof(short));
    float*    inv    = (float*)   alloc((size_t)NNODES * sizeof(float));
    int*      row_off= (int*)     alloc((size_t)NNODES * sizeof(int));
    int*      cntA   = (int*)     alloc((size_t)NNODES * sizeof(int));
    int*      col    = (int*)     alloc((size_t)NBUCK2 * CAP * sizeof(int));
    unsigned* tmp    = (unsigned*)alloc((size_t)NBUCK2 * CAP * sizeof(unsigned));
    int*      gcur   = (int*)     alloc((size_t)NBUCK2 * sizeof(int));
    short*    WT     = (short*)   alloc((size_t)5 * DIM * DIM * sizeof(short));
    float*    pooled = (float*)   alloc((size_t)NGRAPH * DIM * sizeof(float));
    float*    t1     = (float*)   alloc((size_t)NGRAPH * DIM * sizeof(float));

    // ---- init + CSR build ----
    k_init   <<<1, 256, 0, stream>>>(gcur);
    k_scatter<<<SBLOCKS, 512, 0, stream>>>(src, dst, gcur, tmp);
    k_build  <<<NBUILD, 512, 0, stream>>>(tmp, gcur, row_off, cntA, inv, col);

    // ---- weight pre-transpose: WT = [enc_W1, enc_W2, gcn_W0, gcn_W1, gcn_W2]
    k_prepW<<<(DIM * DIM + 255) / 256, 256, 0, stream>>>(enc_W1, WT, 1);
    k_prepW<<<(DIM * DIM + 255) / 256, 256, 0, stream>>>(enc_W2, WT + 16384, 1);
    k_prepW<<<(3 * DIM * DIM + 255) / 256, 256, 0, stream>>>(gcn_W, WT + 2 * 16384, 3);

    // ---- fused encoder: x -> hw0 ----
    k_enc<<<FBLOCKS, 512, 0, stream>>>(x, WT, enc_b1, enc_b2, inv, hwA, NNODES);

    // ---- GCN layers: agg (hwA->hwB) then gemm (hwB->hwA) ----
    const int aggBlocks = (NNODES + 15) / 16;   // 2 nodes/wave, 8 waves/block
    k_agg<<<aggBlocks, 512, 0, stream>>>(hwA, row_off, cntA, col, inv, gcn_b, hwB);
    gemm_mfma<<<FBLOCKS, 256, 0, stream>>>(hwB, WT + 3 * 16384, inv, hwA, NNODES);
    k_agg<<<aggBlocks, 512, 0, stream>>>(hwA, row_off, cntA, col, inv, gcn_b + 128, hwB);
    gemm_mfma<<<FBLOCKS, 256, 0, stream>>>(hwB, WT + 4 * 16384, inv, hwA, NNODES);
    k_agg<<<aggBlocks, 512, 0, stream>>>(hwA, row_off, cntA, col, inv, gcn_b + 256, hwB);

    // ---- pool + decoder ----
    k_pool<<<NGRAPH, 128, 0, stream>>>(hwB, batch, pooled);
    gemm128_f32<<<(NGRAPH + 127) / 128, 256, 0, stream>>>(pooled, dec_W1, dec_b1, t1, NGRAPH);
    k_dec2<<<(NGRAPH * OUTD + 255) / 256, 256, 0, stream>>>(t1, dec_W2, dec_b2, out);
}

// Round 7
// 442.121 us; speedup vs baseline: 1.3368x; 1.1233x over previous
//
#include <hip/hip_runtime.h>

#define NNODES 100000
#define NEDGES 1600000
#define DIM    128
#define OUTD   32
#define NGRAPH 512
#define LDA    136   // padded LDS stride (bf16 elems)

#define NBUCK2  256                          // coarse buckets: dst >> 9
#define BSHIFT  9
#define CAP     12288                        // per-bucket region capacity (mean 8163)
#define EPB2    8192
#define SBLOCKS ((NEDGES + EPB2 - 1) / EPB2) // 196
#define NBUILD  ((NNODES + 511) / 512)       // 196
#define FBLOCKS ((NNODES + 127) / 128)       // 782

using bf16x8 = __attribute__((ext_vector_type(8))) short;
using f32x4  = __attribute__((ext_vector_type(4))) float;

__device__ __forceinline__ short f2bf(float f) {
    unsigned u = __float_as_uint(f);
    unsigned r = (u + 0x7fff + ((u >> 16) & 1)) >> 16;   // RNE
    return (short)r;
}
__device__ __forceinline__ float bf2f(short s) {
    return __uint_as_float(((unsigned)(unsigned short)s) << 16);
}
__device__ __forceinline__ float bf2f_lo(unsigned u) { return __uint_as_float(u << 16); }
__device__ __forceinline__ float bf2f_hi(unsigned u) { return __uint_as_float(u & 0xffff0000u); }

// ============================================================
// Weight pre-transpose: WT[mat][n][k] = bf16(W[mat][k][n])
// ============================================================
__global__ __launch_bounds__(256) void k_prepW(
    const float* __restrict__ W, short* __restrict__ WT, int nmat)
{
    int idx = blockIdx.x * 256 + threadIdx.x;
    if (idx >= nmat * DIM * DIM) return;
    int mat = idx >> 14;
    int rem = idx & 16383;
    int k = rem >> 7, n = rem & 127;
    WT[(size_t)mat * 16384 + n * DIM + k] = f2bf(W[(size_t)mat * 16384 + k * DIM + n]);
}

// ============================================================
// Fused encoder: x -> relu(xW1+b1) -> relu(..W2+b2) -> (..Wg0)*inv -> hw0
// ============================================================
__global__ __launch_bounds__(512, 4) void k_enc(
    const float* __restrict__ x, const short* __restrict__ WT,
    const float* __restrict__ b1, const float* __restrict__ b2,
    const float* __restrict__ inv, short* __restrict__ hw0, int M)
{
    __shared__ short As[128 * LDA];
    __shared__ short Bs[128 * LDA];

    const int tid = threadIdx.x;
    const int m0  = blockIdx.x * 128;

    {
        const int row = tid >> 2, ch = (tid & 3) * 32;
        const int gr  = min(m0 + row, M - 1);
        const float4* sp = (const float4*)(x + (size_t)gr * DIM + ch);
        #pragma unroll
        for (int c = 0; c < 4; ++c) {
            float4 f0 = sp[c * 2], f1 = sp[c * 2 + 1];
            short t8[8] = { f2bf(f0.x), f2bf(f0.y), f2bf(f0.z), f2bf(f0.w),
                            f2bf(f1.x), f2bf(f1.y), f2bf(f1.z), f2bf(f1.w) };
            *(bf16x8*)&As[row * LDA + ch + c * 8] = *(bf16x8*)t8;
        }
    }

    const int wave = tid >> 6, lane = tid & 63;
    const int ml = lane & 15, quad = lane >> 4;
    const int w16 = wave * 16;
    const int brow = tid >> 2, bch = (tid & 3) * 32;

    #pragma unroll
    for (int mat = 0; mat < 3; ++mat) {
        if (mat > 0) __syncthreads();
        const short* wt = WT + (size_t)mat * 16384 + brow * DIM + bch;
        #pragma unroll
        for (int c = 0; c < 4; ++c)
            *(bf16x8*)&Bs[brow * LDA + bch + c * 8] = *(const bf16x8*)(wt + c * 8);
        __syncthreads();

        f32x4 acc[8] = {};
        #pragma unroll
        for (int kk = 0; kk < 4; ++kk) {
            const int k0 = kk * 32 + quad * 8;
            bf16x8 a = *(bf16x8*)&As[(w16 + ml) * LDA + k0];
            #pragma unroll
            for (int ni = 0; ni < 8; ++ni) {
                bf16x8 b = *(bf16x8*)&Bs[(ni * 16 + ml) * LDA + k0];
                acc[ni] = __builtin_amdgcn_mfma_f32_16x16x32_bf16(a, b, acc[ni], 0, 0, 0);
            }
        }
        #pragma unroll
        for (int ni = 0; ni < 8; ++ni) {
            const int colc = ni * 16 + ml;
            #pragma unroll
            for (int r = 0; r < 4; ++r) {
                const int rowl = w16 + quad * 4 + r;
                float v = acc[ni][r];
                if (mat == 0)      v = fmaxf(v + b1[colc], 0.f);
                else if (mat == 1) v = fmaxf(v + b2[colc], 0.f);
                else               v *= inv[min(m0 + rowl, M - 1)];
                As[rowl * LDA + colc] = f2bf(v);
            }
        }
    }

    const int srow = w16 + (lane >> 2), sch = (lane & 3) * 32;
    const int grow = m0 + srow;
    if (grow < M) {
        #pragma unroll
        for (int c = 0; c < 4; ++c)
            *(bf16x8*)(hw0 + (size_t)grow * DIM + sch + c * 8) =
                *(bf16x8*)&As[srow * LDA + sch + c * 8];
    }
}

// ============================================================
// bf16 MFMA GEMM (GCN layers): C = (A @ W)*inv[row], W as bf16 W^T
// ============================================================
__global__ __launch_bounds__(256) void gemm_mfma(
    const short* __restrict__ A, const short* __restrict__ WT,
    const float* __restrict__ inv, short* __restrict__ C, int M)
{
    __shared__ short As[128 * LDA];
    __shared__ short Bs[128 * LDA];

    const int tid = threadIdx.x;
    const int m0  = blockIdx.x * 128;

    #pragma unroll
    for (int i = 0; i < 8; ++i) {
        int idx = tid + i * 256;
        int row = idx >> 4, kg = (idx & 15) << 3;
        int r = min(m0 + row, M - 1);
        *(bf16x8*)&As[row * LDA + kg] = *(const bf16x8*)(A + (size_t)r * DIM + kg);
    }
    #pragma unroll
    for (int i = 0; i < 8; ++i) {
        int idx = tid + i * 256;
        int n = idx >> 4, kg = (idx & 15) << 3;
        *(bf16x8*)&Bs[n * LDA + kg] = *(const bf16x8*)(WT + n * DIM + kg);
    }
    __syncthreads();

    const int wave = tid >> 6, lane = tid & 63;
    const int ml = lane & 15, quad = lane >> 4;
    const int w32 = wave * 32;

    f32x4 acc[2][8] = {};
    #pragma unroll
    for (int kk = 0; kk < 4; ++kk) {
        const int k0 = kk * 32 + quad * 8;
        bf16x8 a0 = *(bf16x8*)&As[(w32 + ml) * LDA + k0];
        bf16x8 a1 = *(bf16x8*)&As[(w32 + 16 + ml) * LDA + k0];
        #pragma unroll
        for (int ni = 0; ni < 8; ++ni) {
            bf16x8 b = *(bf16x8*)&Bs[(ni * 16 + ml) * LDA + k0];
            acc[0][ni] = __builtin_amdgcn_mfma_f32_16x16x32_bf16(a0, b, acc[0][ni], 0, 0, 0);
            acc[1][ni] = __builtin_amdgcn_mfma_f32_16x16x32_bf16(a1, b, acc[1][ni], 0, 0, 0);
        }
    }
    __syncthreads();

    short* Cs = As;
    #pragma unroll
    for (int mi = 0; mi < 2; ++mi) {
        #pragma unroll
        for (int ni = 0; ni < 8; ++ni) {
            const int colc = ni * 16 + ml;
            #pragma unroll
            for (int r = 0; r < 4; ++r) {
                const int row = w32 + mi * 16 + quad * 4 + r;
                float v = acc[mi][ni][r] * inv[min(m0 + row, M - 1)];
                Cs[row * LDA + colc] = f2bf(v);
            }
        }
    }
    __syncthreads();
    #pragma unroll
    for (int i = 0; i < 8; ++i) {
        int idx = tid + i * 256;
        int row = idx >> 4, cg = (idx & 15) << 3;
        int gr = m0 + row;
        if (gr < M)
            *(bf16x8*)(C + (size_t)gr * DIM + cg) = *(bf16x8*)&Cs[row * LDA + cg];
    }
}

// ============================================================
// Aggregation v2: 2 nodes per wave, 32 lanes x uint2 (8B) per node.
// ============================================================
__global__ __launch_bounds__(512) void k_agg(
    const short* __restrict__ hwp, const int* __restrict__ row_off,
    const int* __restrict__ cntA, const int* __restrict__ col,
    const float* __restrict__ inv, const float* __restrict__ bias,
    short* __restrict__ hout)
{
    const int wid  = blockIdx.x * 8 + (threadIdx.x >> 6);
    const int lane = threadIdx.x & 63;
    const int half = lane >> 5;
    const int sl   = lane & 31;
    const int node = wid * 2 + half;
    if (node >= NNODES) return;

    const uint2* hp = (const uint2*)hwp;
    uint2 us = hp[(size_t)node * 32 + sl];
    float a0 = bf2f_lo(us.x), a1 = bf2f_hi(us.x);
    float a2 = bf2f_lo(us.y), a3 = bf2f_hi(us.y);

    const int s = row_off[node];
    const int e = s + cntA[node];
    int j = s;
    for (; j + 3 < e; j += 4) {
        int u0 = col[j], u1 = col[j + 1], u2 = col[j + 2], u3 = col[j + 3];
        uint2 v0 = hp[(size_t)u0 * 32 + sl];
        uint2 v1 = hp[(size_t)u1 * 32 + sl];
        uint2 v2 = hp[(size_t)u2 * 32 + sl];
        uint2 v3 = hp[(size_t)u3 * 32 + sl];
        a0 += bf2f_lo(v0.x) + bf2f_lo(v1.x) + bf2f_lo(v2.x) + bf2f_lo(v3.x);
        a1 += bf2f_hi(v0.x) + bf2f_hi(v1.x) + bf2f_hi(v2.x) + bf2f_hi(v3.x);
        a2 += bf2f_lo(v0.y) + bf2f_lo(v1.y) + bf2f_lo(v2.y) + bf2f_lo(v3.y);
        a3 += bf2f_hi(v0.y) + bf2f_hi(v1.y) + bf2f_hi(v2.y) + bf2f_hi(v3.y);
    }
    for (; j < e; ++j) {
        uint2 v = hp[(size_t)col[j] * 32 + sl];
        a0 += bf2f_lo(v.x); a1 += bf2f_hi(v.x);
        a2 += bf2f_lo(v.y); a3 += bf2f_hi(v.y);
    }
    const float scv = inv[node];
    const float4 bb = ((const float4*)bias)[sl];
    float o0 = fmaxf(fmaf(a0, scv, bb.x), 0.f);
    float o1 = fmaxf(fmaf(a1, scv, bb.y), 0.f);
    float o2 = fmaxf(fmaf(a2, scv, bb.z), 0.f);
    float o3 = fmaxf(fmaf(a3, scv, bb.w), 0.f);
    uint2 o;
    o.x = (unsigned)(unsigned short)f2bf(o0) | ((unsigned)(unsigned short)f2bf(o1) << 16);
    o.y = (unsigned)(unsigned short)f2bf(o2) | ((unsigned)(unsigned short)f2bf(o3) << 16);
    ((uint2*)hout)[(size_t)node * 32 + sl] = o;
}

// ============================================================
// CSR build + init (also zeroes pooled)
// ============================================================
__global__ __launch_bounds__(256) void k_init(int* __restrict__ gcur,
                                              float* __restrict__ pooled) {
    int i = blockIdx.x * 256 + threadIdx.x;
    if (i < NBUCK2) gcur[i] = i * CAP;
    if (i < NGRAPH * DIM) pooled[i] = 0.f;
}

__global__ __launch_bounds__(512) void k_scatter(
    const int* __restrict__ src, const int* __restrict__ dst,
    int* __restrict__ gcur, unsigned* __restrict__ tmp)
{
    __shared__ unsigned short rnk[EPB2];
    __shared__ int h[NBUCK2];
    __shared__ int gbase[NBUCK2];
    const int tid  = threadIdx.x;
    const int base = blockIdx.x * EPB2;
    if (tid < NBUCK2) h[tid] = 0;
    __syncthreads();
    #pragma unroll
    for (int it = 0; it < EPB2 / 512; ++it) {
        int e = base + it * 512 + tid;
        if (e < NEDGES) {
            int b = dst[e] >> BSHIFT;
            rnk[it * 512 + tid] = (unsigned short)atomicAdd(&h[b], 1);
        }
    }
    __syncthreads();
    if (tid < NBUCK2 && h[tid] > 0)
        gbase[tid] = atomicAdd(&gcur[tid], h[tid]);
    __syncthreads();
    #pragma unroll
    for (int it = 0; it < EPB2 / 512; ++it) {
        int e = base + it * 512 + tid;
        if (e < NEDGES) {
            int d = dst[e], sv = src[e];
            int b = d >> BSHIFT;
            int pos = gbase[b] + rnk[it * 512 + tid];
            if (pos < (b + 1) * CAP)
                tmp[pos] = (unsigned)sv | ((unsigned)(d & 511) << 17);
        }
    }
}

__global__ __launch_bounds__(512) void k_build(
    const unsigned* __restrict__ tmp, const int* __restrict__ gcur,
    int* __restrict__ row_off, int* __restrict__ cntA,
    float* __restrict__ inv, int* __restrict__ col)
{
    __shared__ int hist[512], sc[512], lcur[512];
    const int tid   = threadIdx.x;
    const int b     = blockIdx.x;
    const int tbase = b * CAP;
    const int cnt_b = min(gcur[b] - tbase, CAP);
    hist[tid] = 0;
    __syncthreads();
    for (int i = tid; i < cnt_b; i += 512)
        atomicAdd(&hist[(tmp[tbase + i] >> 17) & 511], 1);
    __syncthreads();
    const int hv = hist[tid];
    sc[tid] = hv;
    __syncthreads();
    for (int off = 1; off < 512; off <<= 1) {
        int t = (tid >= off) ? sc[tid - off] : 0;
        __syncthreads();
        sc[tid] += t;
        __syncthreads();
    }
    const int start = tbase + sc[tid] - hv;
    lcur[tid] = start;
    const int node = b * 512 + tid;
    if (node < NNODES) {
        row_off[node] = start;
        cntA[node]    = hv;
        inv[node]     = rsqrtf((float)hv + 1.0f);
    }
    __syncthreads();
    for (int i = tid; i < cnt_b; i += 512) {
        unsigned t = tmp[tbase + i];
        int pos = atomicAdd(&lcur[(t >> 17) & 511], 1);
        col[pos] = (int)(t & 0x1FFFFu);
    }
}

// ============================================================
// Global add pool v2: segmented atomic reduction (batch sorted).
// 782 blocks x 512 thr; wave owns 16 consecutive nodes; lane = 2 feats.
// ============================================================
__global__ __launch_bounds__(512) void k_pool(
    const short* __restrict__ h, const int* __restrict__ batch,
    float* __restrict__ pooled)
{
    const int wave = threadIdx.x >> 6, lane = threadIdx.x & 63;
    const int node0 = blockIdx.x * 128 + wave * 16;
    const unsigned* hp = (const unsigned*)h;

    float gx = 0.f, gy = 0.f;
    int cg = -1;
    #pragma unroll 1
    for (int i = 0; i < 16; ++i) {
        const int node = node0 + i;
        if (node >= NNODES) break;
        const int g = batch[node];
        if (g != cg) {
            if (cg >= 0) {
                atomicAdd(pooled + (size_t)cg * DIM + lane * 2,     gx);
                atomicAdd(pooled + (size_t)cg * DIM + lane * 2 + 1, gy);
            }
            cg = g; gx = 0.f; gy = 0.f;
        }
        unsigned v = hp[(size_t)node * 64 + lane];
        gx += bf2f_lo(v);
        gy += bf2f_hi(v);
    }
    if (cg >= 0) {
        atomicAdd(pooled + (size_t)cg * DIM + lane * 2,     gx);
        atomicAdd(pooled + (size_t)cg * DIM + lane * 2 + 1, gy);
    }
}

// ============================================================
// Decoder (fp32, tiny)
// ============================================================
__global__ __launch_bounds__(256) void gemm128_f32(
    const float* __restrict__ A, const float* __restrict__ W,
    const float* __restrict__ bias, float* __restrict__ C, int M)
{
    __shared__ float As[16][132];
    __shared__ float Bs[16][132];

    const int tid = threadIdx.x;
    const int m0  = blockIdx.x * 128;
    const int tx  = tid & 15;
    const int ty  = tid >> 4;
    const int ar = tid >> 2;
    const int ac = (tid & 3) << 2;
    const int br = tid >> 5;
    const int bc = (tid & 31) << 2;

    float acc[8][8];
    #pragma unroll
    for (int i = 0; i < 8; ++i)
        #pragma unroll
        for (int j = 0; j < 8; ++j) acc[i][j] = 0.f;

    for (int kt = 0; kt < 8; ++kt) {
        const int k0 = kt << 4;
        const int r0 = min(m0 + ar,      M - 1);
        const int r1 = min(m0 + ar + 64, M - 1);
        float4 a0 = *(const float4*)(A + (size_t)r0 * DIM + k0 + ac);
        float4 a1 = *(const float4*)(A + (size_t)r1 * DIM + k0 + ac);
        float4 b0 = *(const float4*)(W + (size_t)(k0 + br)     * DIM + bc);
        float4 b1 = *(const float4*)(W + (size_t)(k0 + br + 8) * DIM + bc);

        __syncthreads();
        As[ac + 0][ar] = a0.x; As[ac + 1][ar] = a0.y;
        As[ac + 2][ar] = a0.z; As[ac + 3][ar] = a0.w;
        As[ac + 0][ar + 64] = a1.x; As[ac + 1][ar + 64] = a1.y;
        As[ac + 2][ar + 64] = a1.z; As[ac + 3][ar + 64] = a1.w;
        *(float4*)&Bs[br][bc]     = b0;
        *(float4*)&Bs[br + 8][bc] = b1;
        __syncthreads();

        #pragma unroll
        for (int kk = 0; kk < 16; ++kk) {
            float4 fa0 = *(const float4*)&As[kk][ty * 8];
            float4 fa1 = *(const float4*)&As[kk][ty * 8 + 4];
            float4 fb0 = *(const float4*)&Bs[kk][tx * 8];
            float4 fb1 = *(const float4*)&Bs[kk][tx * 8 + 4];
            float av[8] = {fa0.x, fa0.y, fa0.z, fa0.w, fa1.x, fa1.y, fa1.z, fa1.w};
            float bv[8] = {fb0.x, fb0.y, fb0.z, fb0.w, fb1.x, fb1.y, fb1.z, fb1.w};
            #pragma unroll
            for (int i = 0; i < 8; ++i)
                #pragma unroll
                for (int j = 0; j < 8; ++j)
                    acc[i][j] = fmaf(av[i], bv[j], acc[i][j]);
        }
    }

    float4 bb0 = *(const float4*)(bias + tx * 8);
    float4 bb1 = *(const float4*)(bias + tx * 8 + 4);
    float bcol[8] = {bb0.x, bb0.y, bb0.z, bb0.w, bb1.x, bb1.y, bb1.z, bb1.w};

    #pragma unroll
    for (int i = 0; i < 8; ++i) {
        const int r = m0 + ty * 8 + i;
        if (r >= M) break;
        float v[8];
        #pragma unroll
        for (int j = 0; j < 8; ++j) v[j] = fmaxf(acc[i][j] + bcol[j], 0.f);
        *(float4*)(C + (size_t)r * DIM + tx * 8)     = make_float4(v[0], v[1], v[2], v[3]);
        *(float4*)(C + (size_t)r * DIM + tx * 8 + 4) = make_float4(v[4], v[5], v[6], v[7]);
    }
}

__global__ __launch_bounds__(256) void k_dec2(
    const float* __restrict__ t1, const float* __restrict__ W2,
    const float* __restrict__ b2, float* __restrict__ out)
{
    int idx = blockIdx.x * 256 + threadIdx.x;
    if (idx >= NGRAPH * OUTD) return;
    int r = idx >> 5, c = idx & 31;
    float acc = b2[c];
    #pragma unroll 8
    for (int k = 0; k < DIM; ++k)
        acc = fmaf(t1[(size_t)r * DIM + k], W2[(size_t)k * OUTD + c], acc);
    out[idx] = acc;
}

// ============================================================
extern "C" void kernel_launch(void* const* d_in, const int* in_sizes, int n_in,
                              void* d_out, int out_size, void* d_ws, size_t ws_size,
                              hipStream_t stream)
{
    const float* x      = (const float*)d_in[0];
    const int*   ei     = (const int*)d_in[1];
    const int*   batch  = (const int*)d_in[2];
    const float* enc_W1 = (const float*)d_in[3];
    const float* enc_b1 = (const float*)d_in[4];
    const float* enc_W2 = (const float*)d_in[5];
    const float* enc_b2 = (const float*)d_in[6];
    const float* gcn_W  = (const float*)d_in[7];
    const float* gcn_b  = (const float*)d_in[8];
    const float* dec_W1 = (const float*)d_in[9];
    const float* dec_b1 = (const float*)d_in[10];
    const float* dec_W2 = (const float*)d_in[11];
    const float* dec_b2 = (const float*)d_in[12];
    float* out = (float*)d_out;

    const int* src = ei;
    const int* dst = ei + NEDGES;

    char* p = (char*)d_ws;
    auto alloc = [&](size_t bytes) -> void* {
        void* r = (void*)p;
        p += (bytes + 255) & ~(size_t)255;
        return r;
    };
    short*    hwA    = (short*)   alloc((size_t)NNODES * DIM * sizeof(short));
    short*    hwB    = (short*)   alloc((size_t)NNODES * DIM * sizeof(short));
    float*    inv    = (float*)   alloc((size_t)NNODES * sizeof(float));
    int*      row_off= (int*)     alloc((size_t)NNODES * sizeof(int));
    int*      cntA   = (int*)     alloc((size_t)NNODES * sizeof(int));
    int*      col    = (int*)     alloc((size_t)NBUCK2 * CAP * sizeof(int));
    unsigned* tmp    = (unsigned*)alloc((size_t)NBUCK2 * CAP * sizeof(unsigned));
    int*      gcur   = (int*)     alloc((size_t)NBUCK2 * sizeof(int));
    short*    WT     = (short*)   alloc((size_t)5 * DIM * DIM * sizeof(short));
    float*    pooled = (float*)   alloc((size_t)NGRAPH * DIM * sizeof(float));
    float*    t1     = (float*)   alloc((size_t)NGRAPH * DIM * sizeof(float));

    // ---- init (cursors + pooled zeros) + CSR build ----
    k_init   <<<(NGRAPH * DIM + 255) / 256, 256, 0, stream>>>(gcur, pooled);
    k_scatter<<<SBLOCKS, 512, 0, stream>>>(src, dst, gcur, tmp);
    k_build  <<<NBUILD, 512, 0, stream>>>(tmp, gcur, row_off, cntA, inv, col);

    // ---- weight pre-transpose: WT = [enc_W1, enc_W2, gcn_W0, gcn_W1, gcn_W2]
    k_prepW<<<(DIM * DIM + 255) / 256, 256, 0, stream>>>(enc_W1, WT, 1);
    k_prepW<<<(DIM * DIM + 255) / 256, 256, 0, stream>>>(enc_W2, WT + 16384, 1);
    k_prepW<<<(3 * DIM * DIM + 255) / 256, 256, 0, stream>>>(gcn_W, WT + 2 * 16384, 3);

    // ---- fused encoder: x -> hw0 ----
    k_enc<<<FBLOCKS, 512, 0, stream>>>(x, WT, enc_b1, enc_b2, inv, hwA, NNODES);

    // ---- GCN layers: agg (hwA->hwB) then gemm (hwB->hwA) ----
    const int aggBlocks = (NNODES + 15) / 16;   // 2 nodes/wave, 8 waves/block
    k_agg<<<aggBlocks, 512, 0, stream>>>(hwA, row_off, cntA, col, inv, gcn_b, hwB);
    gemm_mfma<<<FBLOCKS, 256, 0, stream>>>(hwB, WT + 3 * 16384, inv, hwA, NNODES);
    k_agg<<<aggBlocks, 512, 0, stream>>>(hwA, row_off, cntA, col, inv, gcn_b + 128, hwB);
    gemm_mfma<<<FBLOCKS, 256, 0, stream>>>(hwB, WT + 4 * 16384, inv, hwA, NNODES);
    k_agg<<<aggBlocks, 512, 0, stream>>>(hwA, row_off, cntA, col, inv, gcn_b + 256, hwB);

    // ---- pool + decoder ----
    k_pool<<<FBLOCKS, 512, 0, stream>>>(hwB, batch, pooled);
    gemm128_f32<<<(NGRAPH + 127) / 128, 256, 0, stream>>>(pooled, dec_W1, dec_b1, t1, NGRAPH);
    k_dec2<<<(NGRAPH * OUTD + 255) / 256, 256, 0, stream>>>(t1, dec_W2, dec_b2, out);
}